// Round 1
// baseline (231.018 us; speedup 1.0000x reference)
//
#include <hip/hip_runtime.h>
#include <cstddef>

// Problem constants (fixed by the reference)
#define BD 8
#define TD 256
#define SD 256
#define HD 512

// tanh(x) = 1 - 2/(1 + e^(2x)); v_exp_f32 + v_rcp_f32, saturates correctly at +-inf
__device__ __forceinline__ float fast_tanh(float x) {
    float e = __expf(2.0f * x);                      // inf for big x -> rcp -> 0 -> 1
    return 1.0f - 2.0f * __builtin_amdgcn_rcpf(1.0f + e);
}

// C[m,n] = sum_k A[m,k] * W[n,k]   (A: M x 512 row-major, W: 512 x 512 row-major)
// 64x64 tile, 256 threads, 4x4 microtile, BK=16. Grid: (N/64, M/64).
__global__ __launch_bounds__(256) void proj_kernel(
    const float* __restrict__ A, const float* __restrict__ W,
    float* __restrict__ C)
{
    const int K = HD;
    __shared__ float As[16][68];   // [k][m], +4 pad keeps float4 alignment, breaks conflicts
    __shared__ float Ws[16][68];   // [k][n]

    const int tid = threadIdx.x;
    const int tx = tid & 15, ty = tid >> 4;
    const int m0 = blockIdx.y * 64, n0 = blockIdx.x * 64;

    float acc[4][4] = {};

    const int row = tid >> 2;            // 0..63
    const int kq  = (tid & 3) * 4;       // 0,4,8,12
    const float* Ap = A + (size_t)(m0 + row) * K + kq;
    const float* Wp = W + (size_t)(n0 + row) * K + kq;

    for (int k0 = 0; k0 < K; k0 += 16) {
        float4 av = *(const float4*)(Ap + k0);
        float4 wv = *(const float4*)(Wp + k0);
        As[kq + 0][row] = av.x; As[kq + 1][row] = av.y;
        As[kq + 2][row] = av.z; As[kq + 3][row] = av.w;
        Ws[kq + 0][row] = wv.x; Ws[kq + 1][row] = wv.y;
        Ws[kq + 2][row] = wv.z; Ws[kq + 3][row] = wv.w;
        __syncthreads();

        #pragma unroll
        for (int k = 0; k < 16; ++k) {
            float4 a = *(const float4*)&As[k][ty * 4];
            float4 b = *(const float4*)&Ws[k][tx * 4];
            float ar[4] = {a.x, a.y, a.z, a.w};
            float br[4] = {b.x, b.y, b.z, b.w};
            #pragma unroll
            for (int i = 0; i < 4; ++i)
                #pragma unroll
                for (int j = 0; j < 4; ++j)
                    acc[i][j] += ar[i] * br[j];
        }
        __syncthreads();
    }

    #pragma unroll
    for (int i = 0; i < 4; ++i) {
        float4 o = make_float4(acc[i][0], acc[i][1], acc[i][2], acc[i][3]);
        *(float4*)(C + (size_t)(m0 + ty * 4 + i) * HD + n0 + tx * 4) = o;
    }
}

// One block per (b,t): scores over s, masked softmax, attn_out = w @ enc.
__global__ __launch_bounds__(256) void attn_kernel(
    const float* __restrict__ enc,     // (B,S,H) raw encoder outputs
    const float* __restrict__ enc_f,   // (B,S,H) projected
    const float* __restrict__ qry_f,   // (B,T,H) projected
    const float* __restrict__ v,       // (H)
    const int*   __restrict__ lens,    // (B)
    float* __restrict__ out)           // (B,T,H)
{
    const int bt   = blockIdx.x;
    const int b    = bt >> 8;          // T = 256
    const int tid  = threadIdx.x;
    const int lane = tid & 63;
    const int wave = tid >> 6;

    __shared__ float sc[SD];
    __shared__ float red[256];
    __shared__ float ws[SD];

    // Per-lane fragments: h = lane*8 + j (contiguous float4 pair -> coalesced)
    const float4* qv = (const float4*)(qry_f + (size_t)bt * HD + lane * 8);
    const float4 q0 = qv[0], q1 = qv[1];
    const float4* vv = (const float4*)(v + lane * 8);
    const float4 v0 = vv[0], v1 = vv[1];

    // ---- scores: one wave per s value ----
    for (int s = wave; s < SD; s += 4) {
        const float4* ev = (const float4*)(enc_f + (size_t)(b * SD + s) * HD + lane * 8);
        float4 e0 = ev[0], e1 = ev[1];
        float acc;
        acc  = v0.x * fast_tanh(e0.x + q0.x);
        acc += v0.y * fast_tanh(e0.y + q0.y);
        acc += v0.z * fast_tanh(e0.z + q0.z);
        acc += v0.w * fast_tanh(e0.w + q0.w);
        acc += v1.x * fast_tanh(e1.x + q1.x);
        acc += v1.y * fast_tanh(e1.y + q1.y);
        acc += v1.z * fast_tanh(e1.z + q1.z);
        acc += v1.w * fast_tanh(e1.w + q1.w);
        #pragma unroll
        for (int off = 32; off; off >>= 1)
            acc += __shfl_xor(acc, off);
        if (lane == 0) sc[s] = acc;
    }
    __syncthreads();

    // ---- masked softmax over s (thread tid owns s = tid; S == blockDim) ----
    const int len = lens[b];
    const bool valid = tid < len;
    float x = valid ? sc[tid] : -INFINITY;
    red[tid] = x;
    __syncthreads();
    #pragma unroll
    for (int st = 128; st; st >>= 1) {
        if (tid < st) red[tid] = fmaxf(red[tid], red[tid + st]);
        __syncthreads();
    }
    const float m = red[0];
    __syncthreads();
    float e = valid ? __expf(x - m) : 0.0f;
    red[tid] = e;
    __syncthreads();
    #pragma unroll
    for (int st = 128; st; st >>= 1) {
        if (tid < st) red[tid] += red[tid + st];
        __syncthreads();
    }
    ws[tid] = e * __builtin_amdgcn_rcpf(red[0]);
    __syncthreads();

    // ---- AV: out[h] = sum_s w[s] * enc[b,s,h]; thread owns h = tid, tid+256 ----
    float a0 = 0.0f, a1 = 0.0f;
    const float* ebase = enc + (size_t)b * SD * HD;
    #pragma unroll 8
    for (int s = 0; s < SD; ++s) {
        float w = ws[s];
        a0 += w * ebase[(size_t)s * HD + tid];
        a1 += w * ebase[(size_t)s * HD + tid + 256];
    }
    float* op = out + (size_t)bt * HD;
    op[tid] = a0;
    op[tid + 256] = a1;
}

extern "C" void kernel_launch(void* const* d_in, const int* in_sizes, int n_in,
                              void* d_out, int out_size, void* d_ws, size_t ws_size,
                              hipStream_t stream) {
    const float* query = (const float*)d_in[0];   // (B,T,H)
    const float* enc   = (const float*)d_in[1];   // (B,S,H)
    const int*   lens  = (const int*)d_in[2];     // (B,)  int32
    const float* W_h   = (const float*)d_in[3];   // (H,H)
    const float* W_s   = (const float*)d_in[4];   // (H,H)
    const float* v     = (const float*)d_in[5];   // (H,)
    float* out = (float*)d_out;

    float* enc_f = (float*)d_ws;                                   // 4 MB
    float* qry_f = (float*)((char*)d_ws + (size_t)BD * SD * HD * 4); // 4 MB

    dim3 pgrid(HD / 64, (BD * SD) / 64);   // (8, 32)
    proj_kernel<<<pgrid, 256, 0, stream>>>(enc,   W_h, enc_f);
    proj_kernel<<<pgrid, 256, 0, stream>>>(query, W_s, qry_f);

    attn_kernel<<<BD * TD, 256, 0, stream>>>(enc, enc_f, qry_f, v, lens, out);
}

// Round 3
// 192.966 us; speedup vs baseline: 1.1972x; 1.1972x over previous
//
#include <hip/hip_runtime.h>
#include <cstddef>
#include <math.h>

#define BD 8
#define TD 256
#define SD 256
#define HD 512
#define TB 4                      // t-values per attn block
#define K2F 2.885390081777927f    // 2*log2(e): arg of exp2 for e^(2x)

#if __has_builtin(__builtin_amdgcn_exp2f)
#define EXP2(x) __builtin_amdgcn_exp2f(x)
#else
#define EXP2(x) exp2f(x)
#endif
#define RCP(x) __builtin_amdgcn_rcpf(x)

// Fused projections: blocks y<32 = enc @ W_h^T, y>=32 = query @ W_s^T.
// Output scaled by K2F so attn's exp2 argument is a single add.
// 64x64 tile, 256 threads, 4x4 microtile, BK=16, register-prefetch double buffer.
__global__ __launch_bounds__(256) void proj_kernel(
    const float* __restrict__ enc, const float* __restrict__ qry,
    const float* __restrict__ W_h, const float* __restrict__ W_s,
    float* __restrict__ enc_f, float* __restrict__ qry_f)
{
    const int K = HD;
    __shared__ float As[16][68];
    __shared__ float Ws[16][68];

    const int tid = threadIdx.x;
    const int tx = tid & 15, ty = tid >> 4;
    const int my = blockIdx.y;
    const bool isq = my >= 32;
    const float* A = isq ? qry : enc;
    const float* W = isq ? W_s : W_h;
    float*       C = isq ? qry_f : enc_f;
    const int m0 = (my & 31) * 64, n0 = blockIdx.x * 64;

    float acc[4][4] = {};

    const int row = tid >> 2;            // 0..63
    const int kq  = (tid & 3) * 4;       // 0,4,8,12
    const float* Ap = A + (size_t)(m0 + row) * K + kq;
    const float* Wp = W + (size_t)(n0 + row) * K + kq;

    float4 av = *(const float4*)(Ap);
    float4 wv = *(const float4*)(Wp);

    for (int k0 = 0; k0 < K; k0 += 16) {
        if (k0) __syncthreads();         // previous compute done reading LDS
        As[kq + 0][row] = av.x; As[kq + 1][row] = av.y;
        As[kq + 2][row] = av.z; As[kq + 3][row] = av.w;
        Ws[kq + 0][row] = wv.x; Ws[kq + 1][row] = wv.y;
        Ws[kq + 2][row] = wv.z; Ws[kq + 3][row] = wv.w;
        __syncthreads();
        if (k0 + 16 < K) {               // prefetch next k-tile while computing
            av = *(const float4*)(Ap + k0 + 16);
            wv = *(const float4*)(Wp + k0 + 16);
        }
        #pragma unroll
        for (int k = 0; k < 16; ++k) {
            float4 a = *(const float4*)&As[k][ty * 4];
            float4 b = *(const float4*)&Ws[k][tx * 4];
            float ar[4] = {a.x, a.y, a.z, a.w};
            float br[4] = {b.x, b.y, b.z, b.w};
            #pragma unroll
            for (int i = 0; i < 4; ++i)
                #pragma unroll
                for (int j = 0; j < 4; ++j)
                    acc[i][j] += ar[i] * br[j];
        }
    }

    #pragma unroll
    for (int i = 0; i < 4; ++i) {
        float4 o = make_float4(acc[i][0] * K2F, acc[i][1] * K2F,
                               acc[i][2] * K2F, acc[i][3] * K2F);
        *(float4*)(C + (size_t)(m0 + ty * 4 + i) * HD + n0 + tx * 4) = o;
    }
}

// One block per (b, 4-t group). Thread tid owns score row s=tid.
// score'_s = -2 * sum_h v_h / (1 + exp2(ef + qf))   (Vsum shift cancels in softmax)
__global__ __launch_bounds__(256) void attn_kernel(
    const float* __restrict__ enc,     // (B,S,H) raw
    const float* __restrict__ enc_f,   // (B,S,H) projected*K2F
    const float* __restrict__ qry_f,   // (B,T,H) projected*K2F
    const float* __restrict__ v,       // (H)
    const int*   __restrict__ lens,    // (B)
    float* __restrict__ out)           // (B,T,H)
{
    __shared__ float  lds_e[32 * 257]; // [h_local][s], stride 257 (2-way bank = free)
    __shared__ float4 red[256];        // reduction scratch, then transposed weights

    const int blk = blockIdx.x;        // 0..511
    const int b   = blk >> 6;
    const int t0  = (blk & 63) * TB;
    const int tid = threadIdx.x;

    const float* encb  = enc   + (size_t)b * SD * HD;
    const float* encfb = enc_f + (size_t)b * SD * HD;
    const float* qf    = qry_f + ((size_t)b * TD + t0) * HD;  // block-uniform -> s_load

    float acc[TB] = {0.0f, 0.0f, 0.0f, 0.0f};

    const int sr = tid >> 3;           // staging: row 0..31
    const int hl = (tid & 7) * 4;      // staging: h sub 0,4,..28

    for (int hc = 0; hc < 16; ++hc) {
        if (hc) __syncthreads();
        const int hb = hc * 32;
        #pragma unroll
        for (int p = 0; p < 8; ++p) {
            const int s = p * 32 + sr;
            float4 ev = *(const float4*)(encfb + (size_t)s * HD + hb + hl);
            lds_e[(hl + 0) * 257 + s] = ev.x;
            lds_e[(hl + 1) * 257 + s] = ev.y;
            lds_e[(hl + 2) * 257 + s] = ev.z;
            lds_e[(hl + 3) * 257 + s] = ev.w;
        }
        __syncthreads();
        #pragma unroll 4
        for (int j = 0; j < 32; ++j) {
            const float e  = lds_e[j * 257 + tid];  // conflict-free (2-way)
            const float vj = v[hb + j];             // uniform -> SGPR
            #pragma unroll
            for (int t = 0; t < TB; ++t) {
                float E = EXP2(e + qf[(size_t)t * HD + hb + j]);  // q uniform -> SGPR
                float r = RCP(1.0f + E);            // saturates correctly at +-inf
                acc[t] = fmaf(vj, r, acc[t]);
            }
        }
    }

    // ---- masked softmax over s, TB rows at once ----
    const int len = lens[b];
    const bool valid = tid < len;
    float4 sc4;
    sc4.x = valid ? -2.0f * acc[0] : -INFINITY;
    sc4.y = valid ? -2.0f * acc[1] : -INFINITY;
    sc4.z = valid ? -2.0f * acc[2] : -INFINITY;
    sc4.w = valid ? -2.0f * acc[3] : -INFINITY;

    __syncthreads();                   // lds_e compute done; red[] now safe to use
    red[tid] = sc4;
    __syncthreads();
    #pragma unroll
    for (int st = 128; st; st >>= 1) {
        if (tid < st) {
            float4 a = red[tid], o = red[tid + st];
            a.x = fmaxf(a.x, o.x); a.y = fmaxf(a.y, o.y);
            a.z = fmaxf(a.z, o.z); a.w = fmaxf(a.w, o.w);
            red[tid] = a;
        }
        __syncthreads();
    }
    const float4 m4 = red[0];
    __syncthreads();
    float4 e4;
    e4.x = valid ? __expf(sc4.x - m4.x) : 0.0f;
    e4.y = valid ? __expf(sc4.y - m4.y) : 0.0f;
    e4.z = valid ? __expf(sc4.z - m4.z) : 0.0f;
    e4.w = valid ? __expf(sc4.w - m4.w) : 0.0f;
    red[tid] = e4;
    __syncthreads();
    #pragma unroll
    for (int st = 128; st; st >>= 1) {
        if (tid < st) {
            float4 a = red[tid], o = red[tid + st];
            a.x += o.x; a.y += o.y; a.z += o.z; a.w += o.w;
            red[tid] = a;
        }
        __syncthreads();
    }
    const float4 s4 = red[0];
    __syncthreads();
    float4 w4;
    w4.x = e4.x * RCP(s4.x);
    w4.y = e4.y * RCP(s4.y);
    w4.z = e4.z * RCP(s4.z);
    w4.w = e4.w * RCP(s4.w);
    red[tid] = w4;                     // red[s] = weights (t0..t0+3) for s
    __syncthreads();

    // ---- AV: out[t,h] = sum_s w[t,s] * enc[s,h] ----
    // Thread owns h-float4 f and a t-PAIR (wave-uniform): tids 0-127 -> t{0,1},
    // tids 128-255 -> t{2,3}. Every thread covers ALL s (fixes R2 race).
    const int f  = (tid & 127) * 4;    // h offset
    const bool hi = tid >= 128;        // wave-uniform t-pair select
    float4 oA = {0,0,0,0}, oB = {0,0,0,0};
    #pragma unroll 4
    for (int s = 0; s < SD; ++s) {
        const float4 w = red[s];       // wave-uniform broadcast
        const float wA = hi ? w.z : w.x;
        const float wB = hi ? w.w : w.y;
        const float4 e = *(const float4*)(encb + (size_t)s * HD + f);
        oA.x += wA * e.x; oA.y += wA * e.y; oA.z += wA * e.z; oA.w += wA * e.w;
        oB.x += wB * e.x; oB.y += wB * e.y; oB.z += wB * e.z; oB.w += wB * e.w;
    }
    const int tA = hi ? 2 : 0;
    float* op = out + ((size_t)b * TD + t0) * HD + f;
    *(float4*)(op + (size_t)(tA + 0) * HD) = oA;
    *(float4*)(op + (size_t)(tA + 1) * HD) = oB;
}

extern "C" void kernel_launch(void* const* d_in, const int* in_sizes, int n_in,
                              void* d_out, int out_size, void* d_ws, size_t ws_size,
                              hipStream_t stream) {
    const float* query = (const float*)d_in[0];
    const float* enc   = (const float*)d_in[1];
    const int*   lens  = (const int*)d_in[2];
    const float* W_h   = (const float*)d_in[3];
    const float* W_s   = (const float*)d_in[4];
    const float* v     = (const float*)d_in[5];
    float* out = (float*)d_out;

    float* enc_f = (float*)d_ws;
    float* qry_f = (float*)((char*)d_ws + (size_t)BD * SD * HD * 4);

    dim3 pgrid(HD / 64, 64);           // fused: 32 enc-row blocks + 32 query-row blocks
    proj_kernel<<<pgrid, 256, 0, stream>>>(enc, query, W_h, W_s, enc_f, qry_f);

    attn_kernel<<<BD * (TD / TB), 256, 0, stream>>>(enc, enc_f, qry_f, v, lens, out);
}

// Round 4
// 163.819 us; speedup vs baseline: 1.4102x; 1.1779x over previous
//
#include <hip/hip_runtime.h>
#include <hip/hip_bf16.h>
#include <cstddef>
#include <math.h>

#define BD 8
#define TD 256
#define SD 256
#define HD 512
#define K2F 2.885390081777927f    // 2*log2(e): arg of exp2 for e^(2x)

#if __has_builtin(__builtin_amdgcn_exp2f)
#define EXP2(x) __builtin_amdgcn_exp2f(x)
#else
#define EXP2(x) exp2f(x)
#endif
#define RCP(x) __builtin_amdgcn_rcpf(x)

typedef __attribute__((ext_vector_type(8))) short short8;
typedef __attribute__((ext_vector_type(4))) float float4v;

// fp32 -> bf16 (RNE), raw bits
__device__ __forceinline__ unsigned short bf_hi(float x) {
    union { float f; unsigned u; } v; v.f = x;
    unsigned r = v.u + 0x7fff + ((v.u >> 16) & 1);
    return (unsigned short)(r >> 16);
}
__device__ __forceinline__ float bf_tof(unsigned short h) {
    union { float f; unsigned u; } v; v.u = ((unsigned)h) << 16;
    return v.f;
}

// Split-bf16 MFMA projections.
// Blocks y<32: enc @ W_h^T -> enc_fT, TRANSPOSED layout (B, H, S), scaled K2F.
// Blocks y>=32: qry @ W_s^T -> qry_f, row-major (B, T, H), scaled K2F.
// 64x64 tile, 256 thr (4 waves), 16x16x32_bf16, hi/lo split: err ~2^-16.
__global__ __launch_bounds__(256) void proj_kernel(
    const float* __restrict__ enc, const float* __restrict__ qry,
    const float* __restrict__ W_h, const float* __restrict__ W_s,
    float* __restrict__ enc_fT, float* __restrict__ qry_f)
{
    // row stride 72 halves (144 B): 16B-aligned rows, 2-way-max bank aliasing on b128 frag reads
    __shared__ unsigned short Ah[64 * 72], Al[64 * 72];
    __shared__ unsigned short Bh[64 * 72], Bl[64 * 72];

    const int tid = threadIdx.x;
    const int my  = blockIdx.y;
    const bool isq = my >= 32;
    const float* A = isq ? qry : enc;
    const float* W = isq ? W_s : W_h;
    const int m0 = (my & 31) * 64, n0 = blockIdx.x * 64;

    const int srow = tid >> 2;           // staging row 0..63
    const int sk   = (tid & 3) * 8;      // staging k-offset 0,8,16,24
    const float* Ap = A + (size_t)(m0 + srow) * HD + sk;
    const float* Wp = W + (size_t)(n0 + srow) * HD + sk;

    const int lane = tid & 63;
    const int w    = tid >> 6;           // wave 0..3: row-strip w*16
    const int rf   = lane & 15;          // frag row/col
    const int q    = lane >> 4;          // quad

    float4v acc[4] = {{0,0,0,0},{0,0,0,0},{0,0,0,0},{0,0,0,0}};

    float4 a0 = *(const float4*)(Ap);
    float4 a1 = *(const float4*)(Ap + 4);
    float4 w0 = *(const float4*)(Wp);
    float4 w1 = *(const float4*)(Wp + 4);

    for (int ks = 0; ks < 16; ++ks) {
        if (ks) __syncthreads();
        // convert + stage current k-chunk
        {
            float af[8] = {a0.x,a0.y,a0.z,a0.w,a1.x,a1.y,a1.z,a1.w};
            float wf[8] = {w0.x,w0.y,w0.z,w0.w,w1.x,w1.y,w1.z,w1.w};
            short8 ahv, alv, bhv, blv;
            #pragma unroll
            for (int i = 0; i < 8; ++i) {
                unsigned short h = bf_hi(af[i]);
                ahv[i] = (short)h; alv[i] = (short)bf_hi(af[i] - bf_tof(h));
                h = bf_hi(wf[i]);
                bhv[i] = (short)h; blv[i] = (short)bf_hi(wf[i] - bf_tof(h));
            }
            *(short8*)&Ah[srow * 72 + sk] = ahv;
            *(short8*)&Al[srow * 72 + sk] = alv;
            *(short8*)&Bh[srow * 72 + sk] = bhv;
            *(short8*)&Bl[srow * 72 + sk] = blv;
        }
        __syncthreads();
        if (ks + 1 < 16) {               // prefetch next chunk during MFMA
            const int ko = (ks + 1) * 32;
            a0 = *(const float4*)(Ap + ko);
            a1 = *(const float4*)(Ap + ko + 4);
            w0 = *(const float4*)(Wp + ko);
            w1 = *(const float4*)(Wp + ko + 4);
        }
        short8 ah = *(short8*)&Ah[(w * 16 + rf) * 72 + q * 8];
        short8 al = *(short8*)&Al[(w * 16 + rf) * 72 + q * 8];
        #pragma unroll
        for (int c = 0; c < 4; ++c) {
            short8 bh = *(short8*)&Bh[(c * 16 + rf) * 72 + q * 8];
            short8 bl = *(short8*)&Bl[(c * 16 + rf) * 72 + q * 8];
            acc[c] = __builtin_amdgcn_mfma_f32_16x16x32_bf16(ah, bh, acc[c], 0, 0, 0);
            acc[c] = __builtin_amdgcn_mfma_f32_16x16x32_bf16(ah, bl, acc[c], 0, 0, 0);
            acc[c] = __builtin_amdgcn_mfma_f32_16x16x32_bf16(al, bh, acc[c], 0, 0, 0);
        }
    }

    // Epilogue. C tile (m-local = w*16 + q*4 + r, n-local = c*16 + rf)
    if (!isq) {
        const int b  = m0 >> 8;                  // 4 m-tiles per batch
        const int sb = (m0 & 255) + w * 16 + q * 4;
        float* base = enc_fT + (size_t)b * HD * SD + sb;
        #pragma unroll
        for (int c = 0; c < 4; ++c) {
            float4 o = make_float4(acc[c][0]*K2F, acc[c][1]*K2F, acc[c][2]*K2F, acc[c][3]*K2F);
            *(float4*)(base + (size_t)(n0 + c * 16 + rf) * SD) = o;   // 4 consecutive s, one h
        }
    } else {
        const int mrow = m0 + w * 16 + q * 4;
        #pragma unroll
        for (int c = 0; c < 4; ++c)
            #pragma unroll
            for (int r = 0; r < 4; ++r)
                qry_f[(size_t)(mrow + r) * HD + n0 + c * 16 + rf] = acc[c][r] * K2F;
    }
}

// One block (512 thr) per (b, 4-t group). Thread owns s = tid&255, t-pair = tid>>8.
// score'_s = -2 * sum_h v_h / (1 + exp2(efT + qf))  (Vsum shift cancels in softmax)
__global__ __launch_bounds__(512) void attn_kernel(
    const float* __restrict__ enc,     // (B,S,H) raw
    const float* __restrict__ encT,    // (B,H,S) projected * K2F
    const float* __restrict__ qry_f,   // (B,T,H) projected * K2F
    const float* __restrict__ v,       // (H)
    const int*   __restrict__ lens,    // (B)
    float* __restrict__ out)           // (B,T,H)
{
    __shared__ float  qls[HD * 4];     // [j][t] interleaved, 8 KB
    __shared__ float2 red[512];        // 4 KB

    const int blk = blockIdx.x;        // 0..511
    const int b   = blk >> 6;
    const int t0  = (blk & 63) * 4;
    const int tid = threadIdx.x;
    const int s   = tid & 255;
    const int tp  = tid >> 8;          // 0/1 (wave-uniform): t-pair {0,1} or {2,3}

    // stage q for the 4 t's: qls[j*4+t] = qry_f[b, t0+t, j]
    {
        const float* qf = qry_f + ((size_t)b * TD + t0) * HD;
        float4 qv;
        qv.x = qf[0 * HD + tid]; qv.y = qf[1 * HD + tid];
        qv.z = qf[2 * HD + tid]; qv.w = qf[3 * HD + tid];
        *(float4*)&qls[tid * 4] = qv;
    }
    __syncthreads();

    // ---- scores: no barriers, coalesced encT reads, 2 trans chains per j ----
    const float* encTb = encT + (size_t)b * HD * SD + s;
    float acc0 = 0.0f, acc1 = 0.0f;
    #pragma unroll 8
    for (int j = 0; j < HD; ++j) {
        const float  e  = encTb[(size_t)j * SD];          // coalesced, L2-resident
        const float2 q2 = *(const float2*)&qls[j * 4 + tp * 2];  // LDS broadcast
        const float  vj = v[j];                           // uniform -> s_load
        float r0 = RCP(1.0f + EXP2(e + q2.x));
        float r1 = RCP(1.0f + EXP2(e + q2.y));
        acc0 = fmaf(vj, r0, acc0);
        acc1 = fmaf(vj, r1, acc1);
    }

    // ---- masked softmax over s: two independent half-block reductions ----
    const int len = lens[b];
    const bool valid = s < len;
    float2 sc;
    sc.x = valid ? -2.0f * acc0 : -INFINITY;
    sc.y = valid ? -2.0f * acc1 : -INFINITY;
    red[tid] = sc;
    __syncthreads();
    #pragma unroll
    for (int st = 128; st; st >>= 1) {
        if ((tid & 255) < st) {
            float2 a = red[tid], o = red[tid + st];
            a.x = fmaxf(a.x, o.x); a.y = fmaxf(a.y, o.y);
            red[tid] = a;
        }
        __syncthreads();
    }
    const float2 m2 = red[tp << 8];
    __syncthreads();
    float2 e2;
    e2.x = valid ? __expf(sc.x - m2.x) : 0.0f;
    e2.y = valid ? __expf(sc.y - m2.y) : 0.0f;
    red[tid] = e2;
    __syncthreads();
    #pragma unroll
    for (int st = 128; st; st >>= 1) {
        if ((tid & 255) < st) {
            float2 a = red[tid], o = red[tid + st];
            a.x += o.x; a.y += o.y;
            red[tid] = a;
        }
        __syncthreads();
    }
    const float2 s2 = red[tp << 8];
    __syncthreads();
    float2 w2;
    w2.x = e2.x * RCP(s2.x);
    w2.y = e2.y * RCP(s2.y);
    red[tid] = w2;                     // red[tp*256 + s] = weights for t {2tp, 2tp+1}
    __syncthreads();

    // ---- AV: thread owns h-float4 f = (tid&127)*4 and t = tid>>7 ----
    const int f = (tid & 127) * 4;
    const int t = tid >> 7;            // 0..3, wave-uniform
    const int rb = (t >> 1) << 8;
    const bool hi = t & 1;
    const float* encb = enc + (size_t)b * SD * HD + f;
    float4 o4 = {0, 0, 0, 0};
    #pragma unroll 4
    for (int ss = 0; ss < SD; ++ss) {
        const float2 w = red[rb + ss]; // broadcast
        const float wt = hi ? w.y : w.x;
        const float4 ev = *(const float4*)(encb + (size_t)ss * HD);
        o4.x = fmaf(wt, ev.x, o4.x);
        o4.y = fmaf(wt, ev.y, o4.y);
        o4.z = fmaf(wt, ev.z, o4.z);
        o4.w = fmaf(wt, ev.w, o4.w);
    }
    *(float4*)(out + ((size_t)b * TD + t0 + t) * HD + f) = o4;
}

extern "C" void kernel_launch(void* const* d_in, const int* in_sizes, int n_in,
                              void* d_out, int out_size, void* d_ws, size_t ws_size,
                              hipStream_t stream) {
    const float* query = (const float*)d_in[0];
    const float* enc   = (const float*)d_in[1];
    const int*   lens  = (const int*)d_in[2];
    const float* W_h   = (const float*)d_in[3];
    const float* W_s   = (const float*)d_in[4];
    const float* v     = (const float*)d_in[5];
    float* out = (float*)d_out;

    float* enc_fT = (float*)d_ws;                                     // 4 MB (B,H,S)
    float* qry_f  = (float*)((char*)d_ws + (size_t)BD * SD * HD * 4); // 4 MB (B,T,H)

    dim3 pgrid(HD / 64, 64);           // 32 enc m-tiles + 32 qry m-tiles
    proj_kernel<<<pgrid, 256, 0, stream>>>(enc, query, W_h, W_s, enc_fT, qry_f);

    attn_kernel<<<BD * (TD / 4), 512, 0, stream>>>(enc, enc_fT, qry_f, v, lens, out);
}